// Round 2
// baseline (114949.390 us; speedup 1.0000x reference)
//
#include <hip/hip_runtime.h>

// ---------------------------------------------------------------------------
// NER LSTM (B=256,S=128,E=256,H=512,O=32) — one persistent kernel.
// 256 wgs x 256 threads, 1 block/CU. 8 batch groups (32 rows) x 32 col-group
// wgs (g=blockIdx&7). Recurrent weights in VGPRs as f16 MFMA B-frags.
// R9 vs R8 (R8 failed: fast counter barrier mixed coherence points — MALL
// atomic arrive vs sc0 L2 poll -> stale clean L2 line -> guard escape -> race):
//  1. Fast barrier is now ATOMIC-FREE and entirely sc0/L2: parity-slotted
//     flag lines (2x32 ints per group, each on its own 128B line), arrive =
//     sc0 store flag[cg]=round, wait = sc0 poll __all(flag[idx]==round).
//     Exact-match + parity slots is race-free (wait(r+1) gates any round r+2
//     overwrite of the r-parity slot) and immune to stale values after the
//     init cleanse. Within one XCD there is ONE shared L2 and sc0 bypasses
//     the only private cache (L1), so sc0-everything has a single point of
//     truth — no staleness possible.
//  2. Init cleanse: h slices zeroed with BOTH agent(sc1) and sc0 stores;
//     parity flag slots sc0-zeroed; all drained (vmcnt(0)) BEFORE the agent
//     init flag is published => init-barrier-pass implies L2-visible zeros.
//  3. Slow path = R7 verbatim (counter @ MALL, sc1 transport). Per-group
//     verdict via XCC_ID-valued init flags, as R8.
// Also keeps R8's conflict-free stageFCW / gatherXE remaps (bit-identical).
// ---------------------------------------------------------------------------

#define BN 256
#define SN 128
#define EN 256
#define HN 512
#define ON 32
#define RG 32          // batch rows per group
#define NCG 32         // col-group wgs per group
#define NTHREADS 256
#define XSTR 264       // xe stage row stride (f16): 256 + 8 pad
#define HSTR 520       // h  stage row stride (f16): 512 + 8 pad
#define FSTR 520       // fcw stage row stride (f16): 512 + 8 pad
#define GSTR 68        // gbuf row stride (floats): 64 + 4 pad
#define POLL_GUARD (1 << 20)
#define SLB 128        // slots ints per group: [0..31] init flags, [40] counter,
                       // [64..95] parity-A flags, [96..127] parity-B flags

typedef _Float16 f16;
typedef _Float16 f16x8 __attribute__((ext_vector_type(8)));
typedef _Float16 f16x4 __attribute__((ext_vector_type(4)));
typedef _Float16 f16x2 __attribute__((ext_vector_type(2)));
typedef float f32x4 __attribute__((ext_vector_type(4)));
typedef unsigned u32x4 __attribute__((ext_vector_type(4)));

__device__ __forceinline__ f32x4 MFMA16(f16x8 a, f16x8 b, f32x4 c) {
  return __builtin_amdgcn_mfma_f32_16x16x32_f16(a, b, c, 0, 0, 0);
}

__device__ __forceinline__ float sigf(float x) { return 1.0f / (1.0f + __expf(-x)); }

// Load B-fragment slice of W [4H x K] (row-major) for column `col`:
// lane holds W[col][kt*32 + quad*8 + j], j=0..7.
template<int NKT>
__device__ __forceinline__ void loadW(const float* __restrict__ Wb, int K, int col, int quad,
                                      f16x8* dst) {
  #pragma unroll
  for (int kt = 0; kt < NKT; ++kt) {
    const float* p = Wb + (size_t)col * K + kt * 32 + quad * 8;
    f32x4 a = *(const f32x4*)p;
    f32x4 b = *(const f32x4*)(p + 4);
    f16x8 h;
    h[0] = (f16)a[0]; h[1] = (f16)a[1]; h[2] = (f16)a[2]; h[3] = (f16)a[3];
    h[4] = (f16)b[0]; h[5] = (f16)b[1]; h[6] = (f16)b[2]; h[7] = (f16)b[3];
    dst[kt] = h;
  }
}

// Issue 8 batched dwordx4 stage loads for one [RG x HN] f16 tile (32KB).
// fast: sc0 (XCD L2, group verified same-XCD)   slow: sc1 (MALL, any XCD).
__device__ __forceinline__ void issue8(u32x4* v, const char* __restrict__ src, int tid,
                                       int fast) {
  const char* base = src + tid * 16;
  if (fast) {
    #pragma unroll
    for (int j = 0; j < 8; ++j)
      asm volatile("global_load_dwordx4 %0, %1, off sc0" : "=v"(v[j]) : "v"(base + j * 4096));
  } else {
    #pragma unroll
    for (int j = 0; j < 8; ++j)
      asm volatile("global_load_dwordx4 %0, %1, off sc1" : "=v"(v[j]) : "v"(base + j * 4096));
  }
}
// Scatter the 8 loaded vectors into padded LDS (call after the waitcnt).
__device__ __forceinline__ void write8(f16* dst, const u32x4* v, int tid) {
  #pragma unroll
  for (int j = 0; j < 8; ++j) {
    int u = j * 256 + tid, rr = u >> 6, cc = u & 63;
    *(u32x4*)&dst[rr * HSTR + cc * 8] = v[j];
  }
}

// acc[mt] += stage(rows mt*16..) x Wr   (A[m=lane&15][k=quad*8+j] layout)
template<int NKT>
__device__ __forceinline__ void matmulAcc(f32x4* acc, const f16* stage, int stride,
                                          const f16x8* Wr, int l16, int quad) {
  #pragma unroll
  for (int mt = 0; mt < 2; ++mt) {
    #pragma unroll
    for (int kt = 0; kt < NKT; ++kt) {
      f16x8 a = *(const f16x8*)&stage[(mt * 16 + l16) * stride + kt * 32 + quad * 8];
      acc[mt] = MFMA16(a, Wr[kt], acc[mt]);
    }
  }
}

// Unified barrier arrive. Every wave drains its own vmcnt (covers the asm
// h-stores), then barrier, then tid0 publishes:
//  fast: sc0 store round number into this round's parity flag slot (L2).
//  slow: fire-and-forget MALL atomic add (R7-proven).
__device__ __forceinline__ void arrive_any(int* slots, int g, int cg, int tid, int fast,
                                           int rnd) {
  asm volatile("s_waitcnt vmcnt(0)" ::: "memory");
  __syncthreads();
  if (tid == 0) {
    if (fast) {
      int* p = &slots[g * SLB + ((rnd & 1) ? 64 : 96) + cg];
      asm volatile("global_store_dword %0, %1, off sc0" :: "v"(p), "v"(rnd) : "memory");
    } else {
      int one = 1;
      int* p = &slots[g * SLB + 40];
      asm volatile("global_atomic_add %0, %1, off" :: "v"(p), "v"(one) : "memory");
    }
  }
}

// Unified barrier wait (all waves poll; escape guard latches in LDS).
//  fast: lane idx=tid&31 sc0-polls its parity flag until ALL == rnd.
//  slow: poll the MALL counter until >= ctarget.
__device__ __forceinline__ void wait_any(int* slots, int g, int tid, int fast, int rnd,
                                         int ctarget, int* esc) {
  if (!*esc) {
    int gd = 0;
    if (fast) {
      const int* p = &slots[g * SLB + ((rnd & 1) ? 64 : 96) + (tid & 31)];
      for (;;) {
        int v;
        asm volatile("global_load_dword %0, %1, off sc0\n\ts_waitcnt vmcnt(0)"
                     : "=v"(v) : "v"(p) : "memory");
        if (__all(v == rnd)) break;
        if (++gd > POLL_GUARD) { *esc = 1; break; }
        __builtin_amdgcn_s_sleep(1);
      }
    } else {
      const int* p = &slots[g * SLB + 40];
      for (;;) {
        int v = __hip_atomic_load(p, __ATOMIC_RELAXED, __HIP_MEMORY_SCOPE_AGENT);
        if (v >= ctarget) break;
        if (++gd > POLL_GUARD) { *esc = 1; break; }
        __builtin_amdgcn_s_sleep(1);
      }
    }
  }
  asm volatile("" ::: "memory");
}

// Gather one time-step of embeddings for the group's 32 rows -> xes (f16).
// r=tid&31, sub=tid>>5: octet lanes hit distinct bank groups (conflict-free).
__device__ __forceinline__ void gatherXE(f16* xes, const int* __restrict__ xTok,
                                         const float* __restrict__ emb, int g, int k, int tid) {
  int r = tid & 31, sub = tid >> 5;
  int tok = xTok[(g * RG + r) * SN + k];
  const float* er = emb + (size_t)tok * EN + sub * 32;
  f16* dst = &xes[r * XSTR + sub * 32];
  #pragma unroll
  for (int jj = 0; jj < 32; jj += 8) {
    f32x4 a = *(const f32x4*)(er + jj);
    f32x4 b = *(const f32x4*)(er + jj + 4);
    f16x8 hv;
    hv[0] = (f16)a[0]; hv[1] = (f16)a[1]; hv[2] = (f16)a[2]; hv[3] = (f16)a[3];
    hv[4] = (f16)b[0]; hv[5] = (f16)b[1]; hv[6] = (f16)b[2]; hv[7] = (f16)b[3];
    *(f16x8*)(dst + jj) = hv;
  }
}

// Stage fcw[st] ([ON][HN] fp32) -> LDS f16. Thread t handles f32x4 vectors
// t + j*256: coalesced 1KB/wave global reads, conflict-free ds_write_b64.
// Same RTE cvt per element as before => bit-identical logits.
__device__ __forceinline__ void stageFCW(f16* fcwb, const float* __restrict__ fcw,
                                         int st, int tid) {
  const float* base = fcw + (size_t)st * ON * HN;
  #pragma unroll
  for (int j = 0; j < 16; ++j) {
    int fo = (tid + j * 256) * 4;        // float offset 0..16380
    int col = fo >> 9, k = fo & 511;
    f32x4 a = *(const f32x4*)(base + fo);
    f16x4 hv;
    hv[0] = (f16)a[0]; hv[1] = (f16)a[1]; hv[2] = (f16)a[2]; hv[3] = (f16)a[3];
    *(f16x4*)&fcwb[col * FSTR + k] = hv;
  }
}

// fp32 LSTM pointwise for one cell from a gate buffer + packed f16x2 store.
// fast: sc0 store (XCD L2)   slow: agent atomic store (MALL).
__device__ __forceinline__ void pointwise_store(const float* gb, int row, int d0, float* cv,
                                                unsigned* __restrict__ hout, int g, int cg,
                                                int sub, int fast) {
  const float* gr = gb + row * GSTR + d0;
  union { unsigned u; f16x2 h; } hv;
  #pragma unroll
  for (int j = 0; j < 2; ++j) {
    float vi = gr[j], vf = gr[16 + j], vg = gr[32 + j], vo = gr[48 + j];
    cv[j] = sigf(vf) * cv[j] + sigf(vi) * tanhf(vg);
    hv.h[j] = (f16)(sigf(vo) * tanhf(cv[j]));
  }
  unsigned* p = &hout[(g * RG + row) * 256 + cg * 8 + sub];
  if (fast)
    asm volatile("global_store_dword %0, %1, off sc0" :: "v"(p), "v"(hv.u) : "memory");
  else
    __hip_atomic_store(p, hv.u, __ATOMIC_RELAXED, __HIP_MEMORY_SCOPE_AGENT);
}

__launch_bounds__(NTHREADS, 1)
__global__ void lstm_all(const int* __restrict__ xTok, const float* __restrict__ emb,
    const float* __restrict__ eWih0, const float* __restrict__ eWhh0,
    const float* __restrict__ ebih0, const float* __restrict__ ebhh0,
    const float* __restrict__ eWih1, const float* __restrict__ eWhh1,
    const float* __restrict__ ebih1, const float* __restrict__ ebhh1,
    const float* __restrict__ dWih0, const float* __restrict__ dWhh0,
    const float* __restrict__ dbih0, const float* __restrict__ dbhh0,
    const float* __restrict__ dWih1, const float* __restrict__ dWhh1,
    const float* __restrict__ dbih1, const float* __restrict__ dbhh1,
    const float* __restrict__ fcw, const float* __restrict__ fcb,
    float* __restrict__ dout, char* __restrict__ h0buf, char* __restrict__ h1buf,
    int* __restrict__ slots)
{
  __shared__ __align__(16) char upool[RG * XSTR * 2];  // enc: xe stage | dec: lbuf + w0d
  __shared__ __align__(16) f16 h0s[RG * HSTR];
  __shared__ __align__(16) f16 h1s[RG * HSTR];
  __shared__ __align__(16) f16 fcwb[ON * FSTR];
  __shared__ float gbuf0[RG * GSTR];
  __shared__ float gbuf1[RG * GSTR];
  __shared__ int amaxlds[RG];
  __shared__ int esc;
  __shared__ int fastlds;

  f16*   xes  = (f16*)upool;
  float* lbuf = (float*)upool;            // [RG][33] logits (decoder only)
  float* w0d  = (float*)(upool + 4352);   // [64][32] dec_Wih0 slice (decoder only)

  const int tid  = threadIdx.x;
  const int g    = blockIdx.x & 7;        // batch group
  const int cg   = blockIdx.x >> 3;       // col-group within group, 0..31
  const int w    = tid >> 6;              // wave = gate index 0..3
  const int lane = tid & 63;
  const int quad = lane >> 4;
  const int l16  = lane & 15;
  const int colg = w * HN + cg * 16 + l16;  // global gate column (2048-space)
  const int urow = tid >> 3;              // pointwise: row 0..31
  const int ud0  = (tid & 7) * 2;         // pointwise: dim pair base
  int rnd = 0;                            // barrier round (fast flag value)
  int ctarget = 0;                        // cumulative counter target (slow)
  if (tid == 0) esc = 0;

  int myxcc = 0;
  asm volatile("s_getreg_b32 %0, hwreg(HW_REG_XCC_ID)" : "=s"(myxcc));

  // ---- encoder weights -> register B-fragments
  f16x8 Wi0r[8], Wh0r[16], Wi1r[16], Wh1r[16];
  loadW<8>(eWih0, EN, colg, quad, Wi0r);
  loadW<16>(eWhh0, HN, colg, quad, Wh0r);
  loadW<16>(eWih1, HN, colg, quad, Wi1r);
  loadW<16>(eWhh1, HN, colg, quad, Wh1r);
  float bias0 = ebih0[colg] + ebhh0[colg];
  float bias1 = ebih1[colg] + ebhh1[colg];

  // ---- xe(0) pre-gather; zero h(-1) (parity 1) via BOTH paths; zero cells
  gatherXE(xes, xTok, emb, g, 0, tid);
  float c0[2] = {0.f, 0.f}, c1[2] = {0.f, 0.f};
  {
    unsigned idx = (unsigned)(BN * 256 + (g * RG + urow) * 256 + cg * 8 + (tid & 7));
    unsigned* p0 = (unsigned*)h0buf + idx;
    unsigned* p1 = (unsigned*)h1buf + idx;
    __hip_atomic_store(p0, 0u, __ATOMIC_RELAXED, __HIP_MEMORY_SCOPE_AGENT);
    __hip_atomic_store(p1, 0u, __ATOMIC_RELAXED, __HIP_MEMORY_SCOPE_AGENT);
    unsigned z = 0;
    asm volatile("global_store_dword %0, %1, off sc0" :: "v"(p0), "v"(z) : "memory");
    asm volatile("global_store_dword %0, %1, off sc0" :: "v"(p1), "v"(z) : "memory");
  }
  // ---- INIT barrier (agent/MALL domain, R7-proven) + L2 cleanse.
  // Per-wave vmcnt drain + barrier => all h-zero stores (both paths) retired.
  // tid0 then: counter reset (agent), parity-flag sc0 zero (L2 cleanse),
  // drain, THEN publish init flag (agent, value 1+XCC_ID). So any wg that
  // sees all 32 init flags also has: counter reset visible, h zeros visible
  // on both paths, parity slots == 0 in the XCD L2.
  asm volatile("s_waitcnt vmcnt(0)" ::: "memory");
  __syncthreads();
  if (tid == 0) {
    __hip_atomic_store(&slots[g * SLB + 40], 0, __ATOMIC_RELAXED, __HIP_MEMORY_SCOPE_AGENT);
    int z = 0;
    int* pa = &slots[g * SLB + 64 + cg];
    int* pb = &slots[g * SLB + 96 + cg];
    asm volatile("global_store_dword %0, %1, off sc0" :: "v"(pa), "v"(z) : "memory");
    asm volatile("global_store_dword %0, %1, off sc0" :: "v"(pb), "v"(z) : "memory");
    asm volatile("s_waitcnt vmcnt(0)" ::: "memory");
    __hip_atomic_store(&slots[g * SLB + cg], 1 + myxcc, __ATOMIC_RELAXED,
                       __HIP_MEMORY_SCOPE_AGENT);
  }
  int fast;
  {
    int v = 0;
    if (!esc) {
      int idx = tid & 31;
      int gd = 0;
      for (;;) {
        v = __hip_atomic_load(&slots[g * SLB + idx], __ATOMIC_RELAXED,
                              __HIP_MEMORY_SCOPE_AGENT);
        if (__all(v >= 1)) break;
        if (++gd > POLL_GUARD) { esc = 1; break; }
        __builtin_amdgcn_s_sleep(1);
      }
    }
    int ok = __all(v == 1 + myxcc) && !esc;
    if (tid == 0) fastlds = ok ? 1 : 0;
  }
  __syncthreads();
  fast = fastlds;

  // ================= encoder: interval k does cell0@k + cell1@(k-1)
  for (int k = 0; k <= SN; ++k) {
    u32x4 v0[8], v1[8];
    issue8(v0, h0buf + (size_t)((k - 1) & 1) * BN * HN * 2 + (size_t)(g * RG) * HN * 2, tid, fast);
    if (k >= 1)
      issue8(v1, h1buf + (size_t)(k & 1) * BN * HN * 2 + (size_t)(g * RG) * HN * 2, tid, fast);

    f32x4 acc0[2], acc1[2];
    if (k < SN) {   // xe part of cell0 overlaps the stage loads
      f32x4 b0; b0[0] = bias0; b0[1] = bias0; b0[2] = bias0; b0[3] = bias0;
      acc0[0] = b0; acc0[1] = b0;
      matmulAcc<8>(acc0, xes, XSTR, Wi0r, l16, quad);
    }
    if (k >= 1) asm volatile("s_waitcnt vmcnt(8)" ::: "memory");  // h0 batch retired
    else        asm volatile("s_waitcnt vmcnt(0)" ::: "memory");
    write8(h0s, v0, tid);
    __syncthreads();
    if (k < SN) matmulAcc<16>(acc0, h0s, HSTR, Wh0r, l16, quad);   // h1 still in flight
    if (k >= 1) {
      f32x4 b1; b1[0] = bias1; b1[1] = bias1; b1[2] = bias1; b1[3] = bias1;
      acc1[0] = b1; acc1[1] = b1;
      matmulAcc<16>(acc1, h0s, HSTR, Wi1r, l16, quad);
      asm volatile("s_waitcnt vmcnt(0)" ::: "memory");
      write8(h1s, v1, tid);
      __syncthreads();
      matmulAcc<16>(acc1, h1s, HSTR, Wh1r, l16, quad);
    }

    // merged exchange: both cells, one sync, one pointwise pass
    #pragma unroll
    for (int mt = 0; mt < 2; ++mt) {
      #pragma unroll
      for (int i = 0; i < 4; ++i) {
        int rr = (mt * 16 + quad * 4 + i) * GSTR + w * 16 + l16;
        if (k < SN) gbuf0[rr] = acc0[mt][i];
        if (k >= 1) gbuf1[rr] = acc1[mt][i];
      }
    }
    __syncthreads();
    if (k < SN)
      pointwise_store(gbuf0, urow, ud0, c0,
                      (unsigned*)(h0buf + (size_t)(k & 1) * BN * HN * 2), g, cg, tid & 7, fast);
    if (k >= 1)
      pointwise_store(gbuf1, urow, ud0, c1,
                      (unsigned*)(h1buf + (size_t)((k - 1) & 1) * BN * HN * 2), g, cg, tid & 7,
                      fast);

    ++rnd; ctarget += NCG;
    arrive_any(slots, g, cg, tid, fast, rnd);
    if (k < SN - 1) gatherXE(xes, xTok, emb, g, k + 1, tid);   // hidden in the gap
    __syncthreads();   // gather-complete guard
    wait_any(slots, g, tid, fast, rnd, ctarget, &esc);
  }

  // ================= decoder setup: swap weight regs to decoder weights
  loadW<16>(dWhh0, HN, colg, quad, Wh0r);
  loadW<16>(dWih1, HN, colg, quad, Wi1r);
  loadW<16>(dWhh1, HN, colg, quad, Wh1r);
  bias0 = dbih0[colg] + dbhh0[colg];
  bias1 = dbih1[colg] + dbhh1[colg];
  {   // dec_Wih0 slice [64 owned cols][32 inputs] -> LDS (one-hot gather table)
    int cl = tid >> 2, i0 = (tid & 3) * 8;
    int gcol = (cl >> 4) * HN + cg * 16 + (cl & 15);
    const float* p = dWih0 + (size_t)gcol * ON + i0;
    #pragma unroll
    for (int j = 0; j < 8; ++j) w0d[cl * 32 + i0 + j] = p[j];
  }
  if (tid < RG) amaxlds[tid] = 0;   // xin(0) = one-hot(0)
  // h0s holds h0@127 (staged at k=128); h1buf parity1 = h1@127; c0,c1 carry.

  // ================= decoder: I1 = [fc+softmax+amax@(t-1)] + cell0@t ; I2 = cell1@t
  for (int t = 0; t <= SN; ++t) {
    u32x4 v0[8];
    issue8(v0, h1buf + (size_t)((t - 1) & 1) * BN * HN * 2 + (size_t)(g * RG) * HN * 2, tid, fast);
    float fb = 0.f;
    if (t >= 1) fb = fcb[(t - 1) * ON + ((w >> 1) * 16 + l16)];   // early, off-chain-ish

    f32x4 acc0[2];
    if (t < SN) {   // Whh0 part of cell0 (h0s ready) overlaps the h1 stage
      acc0[0] = f32x4{0.f, 0.f, 0.f, 0.f}; acc0[1] = acc0[0];
      matmulAcc<16>(acc0, h0s, HSTR, Wh0r, l16, quad);
    }
    asm volatile("s_waitcnt vmcnt(0)" ::: "memory");
    write8(h1s, v0, tid);
    __syncthreads();

    if (t >= 1) {
      int fmt = w & 1, fnt = w >> 1;
      int colo = fnt * 16 + l16;
      f32x4 afc = {0.f, 0.f, 0.f, 0.f};
      #pragma unroll
      for (int kt = 0; kt < 16; ++kt) {   // B-frags from LDS (prefetched in I2 gap)
        f16x8 bf = *(const f16x8*)&fcwb[colo * FSTR + kt * 32 + quad * 8];
        f16x8 av = *(const f16x8*)&h1s[(fmt * 16 + l16) * HSTR + kt * 32 + quad * 8];
        afc = MFMA16(av, bf, afc);
      }
      #pragma unroll
      for (int i = 0; i < 4; ++i)
        lbuf[(fmt * 16 + quad * 4 + i) * 33 + colo] = afc[i] + fb;
      __syncthreads();
      {   // parallel softmax + argmax: 8 threads per row, shfl_xor reductions
        int st = t - 1;
        int row = tid >> 3, s = tid & 7, cbase = s * 4;
        float vv[4];
        #pragma unroll
        for (int j = 0; j < 4; ++j) vv[j] = lbuf[row * 33 + cbase + j];
        float mx = vv[0]; int bi = cbase;
        #pragma unroll
        for (int j = 1; j < 4; ++j)
          if (vv[j] > mx) { mx = vv[j]; bi = cbase + j; }
        #pragma unroll
        for (int m = 1; m < 8; m <<= 1) {
          float om = __shfl_xor(mx, m);
          int   ob = __shfl_xor(bi, m);
          if (om > mx || (om == mx && ob < bi)) { mx = om; bi = ob; }
        }
        float e[4], ss = 0.f;
        #pragma unroll
        for (int j = 0; j < 4; ++j) { e[j] = __expf(vv[j] - mx); ss += e[j]; }
        #pragma unroll
        for (int m = 1; m < 8; m <<= 1) ss += __shfl_xor(ss, m);
        if (s == 0) amaxlds[row] = bi;
        if (cg == 0) {
          float inv = 1.0f / ss;
          float* op = dout + ((size_t)(g * RG + row) * SN + st) * ON + cbase;
          #pragma unroll
          for (int j = 0; j < 4; ++j) op[j] = e[j] * inv;
        }
      }
      __syncthreads();
    }

    if (t < SN) {   // add bias + one-hot gather(dec_Wih0, amax), then exchange
      #pragma unroll
      for (int mt = 0; mt < 2; ++mt) {
        #pragma unroll
        for (int i = 0; i < 4; ++i) {
          int row = mt * 16 + quad * 4 + i;
          acc0[mt][i] += bias0 + w0d[(w * 16 + l16) * 32 + amaxlds[row]];
        }
      }
      #pragma unroll
      for (int mt = 0; mt < 2; ++mt) {
        #pragma unroll
        for (int i = 0; i < 4; ++i)
          gbuf0[(mt * 16 + quad * 4 + i) * GSTR + w * 16 + l16] = acc0[mt][i];
      }
      __syncthreads();
      pointwise_store(gbuf0, urow, ud0, c0,
                      (unsigned*)(h0buf + (size_t)(t & 1) * BN * HN * 2), g, cg, tid & 7, fast);
    }
    ++rnd; ctarget += NCG;
    arrive_any(slots, g, cg, tid, fast, rnd);
    wait_any(slots, g, tid, fast, rnd, ctarget, &esc);

    if (t < SN) {   // I2: cell1@t : h0@t@Wih1^T + h1@(t-1)@Whh1^T + b
      u32x4 v2[8];
      issue8(v2, h0buf + (size_t)(t & 1) * BN * HN * 2 + (size_t)(g * RG) * HN * 2, tid, fast);
      f32x4 acc1[2];
      f32x4 b1; b1[0] = bias1; b1[1] = bias1; b1[2] = bias1; b1[3] = bias1;
      acc1[0] = b1; acc1[1] = b1;
      matmulAcc<16>(acc1, h1s, HSTR, Wh1r, l16, quad);   // h1@(t-1), overlaps stage
      asm volatile("s_waitcnt vmcnt(0)" ::: "memory");
      write8(h0s, v2, tid);
      __syncthreads();
      matmulAcc<16>(acc1, h0s, HSTR, Wi1r, l16, quad);
      #pragma unroll
      for (int mt = 0; mt < 2; ++mt) {
        #pragma unroll
        for (int i = 0; i < 4; ++i)
          gbuf0[(mt * 16 + quad * 4 + i) * GSTR + w * 16 + l16] = acc1[mt][i];
      }
      __syncthreads();
      pointwise_store(gbuf0, urow, ud0, c1,
                      (unsigned*)(h1buf + (size_t)(t & 1) * BN * HN * 2), g, cg, tid & 7, fast);
      ++rnd; ctarget += NCG;
      arrive_any(slots, g, cg, tid, fast, rnd);
      stageFCW(fcwb, fcw, t, tid);   // fcw[st=t] for next I1 — hidden in the gap
      __syncthreads();               // staging-complete guard
      wait_any(slots, g, tid, fast, rnd, ctarget, &esc);
    }
  }
}

extern "C" void kernel_launch(void* const* d_in, const int* in_sizes, int n_in,
                              void* d_out, int out_size, void* d_ws, size_t ws_size,
                              hipStream_t stream) {
  (void)in_sizes; (void)n_in; (void)out_size; (void)ws_size;
  const int*   xTok  = (const int*)d_in[0];
  const float* emb   = (const float*)d_in[1];
  const float* eWih0 = (const float*)d_in[2];
  const float* eWhh0 = (const float*)d_in[3];
  const float* ebih0 = (const float*)d_in[4];
  const float* ebhh0 = (const float*)d_in[5];
  const float* eWih1 = (const float*)d_in[6];
  const float* eWhh1 = (const float*)d_in[7];
  const float* ebih1 = (const float*)d_in[8];
  const float* ebhh1 = (const float*)d_in[9];
  const float* dWih0 = (const float*)d_in[10];
  const float* dWhh0 = (const float*)d_in[11];
  const float* dbih0 = (const float*)d_in[12];
  const float* dbhh0 = (const float*)d_in[13];
  const float* dWih1 = (const float*)d_in[14];
  const float* dWhh1 = (const float*)d_in[15];
  const float* dbih1 = (const float*)d_in[16];
  const float* dbhh1 = (const float*)d_in[17];
  const float* fcw   = (const float*)d_in[18];
  const float* fcb   = (const float*)d_in[19];

  // ws layout: h0buf [2][256][512] f16 (512KB) | h1buf (512KB) |
  // slots [8][128] int (4KB; per group: [0..31] init flags [agent],
  // [40] counter [slow path], [64..95] parity-A, [96..127] parity-B flags)
  char* h0buf = (char*)d_ws;
  char* h1buf = (char*)d_ws + (size_t)2 * BN * HN * 2;
  int*  slots = (int*)((char*)d_ws + (size_t)4 * BN * HN * 2);

  hipLaunchKernelGGL(lstm_all, dim3(256), dim3(NTHREADS), 0, stream,
                     xTok, emb, eWih0, eWhh0, ebih0, ebhh0, eWih1, eWhh1, ebih1, ebhh1,
                     dWih0, dWhh0, dbih0, dbhh0, dWih1, dWhh1, dbih1, dbhh1,
                     fcw, fcb, (float*)d_out, h0buf, h1buf, slots);
}

// Round 3
// 2826.876 us; speedup vs baseline: 40.6631x; 40.6631x over previous
//
#include <hip/hip_runtime.h>

// ---------------------------------------------------------------------------
// NER LSTM (B=256,S=128,E=256,H=512,O=32) — one persistent kernel.
// 256 wgs x 256 threads, 1 block/CU. 8 batch groups (32 rows) x 32 col-group
// wgs (g=blockIdx&7). Recurrent weights in VGPRs as f16 MFMA B-frags.
// R10 vs R9 (R9: fast sc0 polls hit stale per-CU L1 -> guard escape ->
// 150ms burns + races; sc0-only loads do NOT bypass L1):
//  1. Fast barrier = ATOMIC counter at slots[g*128+64] (own cache line).
//     Arrive: plain global_atomic_add (no return). Wait: tid0-only poll via
//     global_atomic_add of 0 with sc0 (returns old value) — atomics execute
//     at a cache point, NEVER in L1, and arrive/poll use the SAME instruction
//     so they meet at the same point regardless of which level that is
//     (XCD L2 hoped, MALL fallback = R7-speed flags, still correct).
//     Wait ends with __syncthreads releasing the wg + buffer_inv (L1
//     invalidate, the gfx940+ acquire primitive) so the sc0 DATA loads that
//     follow can never hit a stale L1 line.
//  2. Two-phase init: phase 1 = proven agent flag barrier (flag = 1+XCC_ID,
//     doubles as same-XCD verdict); cleanses slow counter + fast-ready slot
//     in the agent domain only (mixed-placement-safe: no L2 dirtying).
//     Phase 2 (fast groups only): cg0 sc0-resets the fast counter, drains,
//     then publishes fast-ready via agent store; wgs poll it agent-side.
//  3. Transport: sc0 stores/loads when fast (+post-wait buffer_inv), R7 sc1
//     when slow. Slow path logic is verbatim R7 (proven 2.4ms).
// Keeps R9's conflict-free stageFCW / gatherXE remaps (bit-identical).
// ---------------------------------------------------------------------------

#define BN 256
#define SN 128
#define EN 256
#define HN 512
#define ON 32
#define RG 32          // batch rows per group
#define NCG 32         // col-group wgs per group
#define NTHREADS 256
#define XSTR 264       // xe stage row stride (f16): 256 + 8 pad
#define HSTR 520       // h  stage row stride (f16): 512 + 8 pad
#define FSTR 520       // fcw stage row stride (f16): 512 + 8 pad
#define GSTR 68        // gbuf row stride (floats): 64 + 4 pad
#define POLL_GUARD (1 << 20)
#define SLB 128        // slots ints per group: [0..31] init flags (1+XCC),
                       // [34] fast-ready, [40] slow counter, [64] fast counter

typedef _Float16 f16;
typedef _Float16 f16x8 __attribute__((ext_vector_type(8)));
typedef _Float16 f16x4 __attribute__((ext_vector_type(4)));
typedef _Float16 f16x2 __attribute__((ext_vector_type(2)));
typedef float f32x4 __attribute__((ext_vector_type(4)));
typedef unsigned u32x4 __attribute__((ext_vector_type(4)));

__device__ __forceinline__ f32x4 MFMA16(f16x8 a, f16x8 b, f32x4 c) {
  return __builtin_amdgcn_mfma_f32_16x16x32_f16(a, b, c, 0, 0, 0);
}

__device__ __forceinline__ float sigf(float x) { return 1.0f / (1.0f + __expf(-x)); }

// Load B-fragment slice of W [4H x K] (row-major) for column `col`:
// lane holds W[col][kt*32 + quad*8 + j], j=0..7.
template<int NKT>
__device__ __forceinline__ void loadW(const float* __restrict__ Wb, int K, int col, int quad,
                                      f16x8* dst) {
  #pragma unroll
  for (int kt = 0; kt < NKT; ++kt) {
    const float* p = Wb + (size_t)col * K + kt * 32 + quad * 8;
    f32x4 a = *(const f32x4*)p;
    f32x4 b = *(const f32x4*)(p + 4);
    f16x8 h;
    h[0] = (f16)a[0]; h[1] = (f16)a[1]; h[2] = (f16)a[2]; h[3] = (f16)a[3];
    h[4] = (f16)b[0]; h[5] = (f16)b[1]; h[6] = (f16)b[2]; h[7] = (f16)b[3];
    dst[kt] = h;
  }
}

// Issue 8 batched dwordx4 stage loads for one [RG x HN] f16 tile (32KB).
// fast: sc0 (XCD L2; consumer L1 freshly invalidated)  slow: sc1 (MALL).
__device__ __forceinline__ void issue8(u32x4* v, const char* __restrict__ src, int tid,
                                       int fast) {
  const char* base = src + tid * 16;
  if (fast) {
    #pragma unroll
    for (int j = 0; j < 8; ++j)
      asm volatile("global_load_dwordx4 %0, %1, off sc0" : "=v"(v[j]) : "v"(base + j * 4096));
  } else {
    #pragma unroll
    for (int j = 0; j < 8; ++j)
      asm volatile("global_load_dwordx4 %0, %1, off sc1" : "=v"(v[j]) : "v"(base + j * 4096));
  }
}
// Scatter the 8 loaded vectors into padded LDS (call after the waitcnt).
__device__ __forceinline__ void write8(f16* dst, const u32x4* v, int tid) {
  #pragma unroll
  for (int j = 0; j < 8; ++j) {
    int u = j * 256 + tid, rr = u >> 6, cc = u & 63;
    *(u32x4*)&dst[rr * HSTR + cc * 8] = v[j];
  }
}

// acc[mt] += stage(rows mt*16..) x Wr   (A[m=lane&15][k=quad*8+j] layout)
template<int NKT>
__device__ __forceinline__ void matmulAcc(f32x4* acc, const f16* stage, int stride,
                                          const f16x8* Wr, int l16, int quad) {
  #pragma unroll
  for (int mt = 0; mt < 2; ++mt) {
    #pragma unroll
    for (int kt = 0; kt < NKT; ++kt) {
      f16x8 a = *(const f16x8*)&stage[(mt * 16 + l16) * stride + kt * 32 + quad * 8];
      acc[mt] = MFMA16(a, Wr[kt], acc[mt]);
    }
  }
}

// Barrier arrive. Every wave drains its own vmcnt (covers the asm h-stores),
// then barrier, then tid0 fires one atomic add into the path's counter.
// Same plain add instruction on both paths => same execution point as the
// matching poll (fast: add-0 RMW; slow: agent load, R7-proven).
__device__ __forceinline__ void arrive_any(int* slots, int g, int tid, int fast) {
  asm volatile("s_waitcnt vmcnt(0)" ::: "memory");
  __syncthreads();
  if (tid == 0) {
    int one = 1;
    int* p = &slots[g * SLB + (fast ? 64 : 40)];
    asm volatile("global_atomic_add %0, %1, off" :: "v"(p), "v"(one) : "memory");
  }
}

// Barrier wait.
//  fast: tid0 polls via returning atomic-add-0 (bypasses L1 by nature, same
//        point as arrives), then __syncthreads releases the wg, then
//        buffer_inv invalidates L1 so following sc0 data loads read the L2.
//  slow: all waves poll the MALL counter (verbatim R7).
__device__ __forceinline__ void wait_any(int* slots, int g, int tid, int fast,
                                         int ctarget, int* esc) {
  if (fast) {
    if (tid == 0 && !*esc) {
      int* p = &slots[g * SLB + 64];
      int gd = 0;
      for (;;) {
        int old, zero = 0;
        asm volatile("global_atomic_add %0, %1, %2, off sc0\n\ts_waitcnt vmcnt(0)"
                     : "=v"(old) : "v"(p), "v"(zero) : "memory");
        if (old >= ctarget) break;
        if (++gd > POLL_GUARD) { *esc = 1; break; }
        __builtin_amdgcn_s_sleep(1);
      }
    }
    __syncthreads();
    asm volatile("buffer_inv" ::: "memory");
  } else {
    if (!*esc) {
      const int* p = &slots[g * SLB + 40];
      int gd = 0;
      for (;;) {
        int v = __hip_atomic_load(p, __ATOMIC_RELAXED, __HIP_MEMORY_SCOPE_AGENT);
        if (v >= ctarget) break;
        if (++gd > POLL_GUARD) { *esc = 1; break; }
        __builtin_amdgcn_s_sleep(1);
      }
    }
  }
  asm volatile("" ::: "memory");
}

// Gather one time-step of embeddings for the group's 32 rows -> xes (f16).
// r=tid&31, sub=tid>>5: octet lanes hit distinct bank groups (conflict-free).
__device__ __forceinline__ void gatherXE(f16* xes, const int* __restrict__ xTok,
                                         const float* __restrict__ emb, int g, int k, int tid) {
  int r = tid & 31, sub = tid >> 5;
  int tok = xTok[(g * RG + r) * SN + k];
  const float* er = emb + (size_t)tok * EN + sub * 32;
  f16* dst = &xes[r * XSTR + sub * 32];
  #pragma unroll
  for (int jj = 0; jj < 32; jj += 8) {
    f32x4 a = *(const f32x4*)(er + jj);
    f32x4 b = *(const f32x4*)(er + jj + 4);
    f16x8 hv;
    hv[0] = (f16)a[0]; hv[1] = (f16)a[1]; hv[2] = (f16)a[2]; hv[3] = (f16)a[3];
    hv[4] = (f16)b[0]; hv[5] = (f16)b[1]; hv[6] = (f16)b[2]; hv[7] = (f16)b[3];
    *(f16x8*)(dst + jj) = hv;
  }
}

// Stage fcw[st] ([ON][HN] fp32) -> LDS f16. Thread t handles f32x4 vectors
// t + j*256: coalesced 1KB/wave global reads, conflict-free ds_write_b64.
// Same RTE cvt per element as before => bit-identical logits.
__device__ __forceinline__ void stageFCW(f16* fcwb, const float* __restrict__ fcw,
                                         int st, int tid) {
  const float* base = fcw + (size_t)st * ON * HN;
  #pragma unroll
  for (int j = 0; j < 16; ++j) {
    int fo = (tid + j * 256) * 4;        // float offset 0..16380
    int col = fo >> 9, k = fo & 511;
    f32x4 a = *(const f32x4*)(base + fo);
    f16x4 hv;
    hv[0] = (f16)a[0]; hv[1] = (f16)a[1]; hv[2] = (f16)a[2]; hv[3] = (f16)a[3];
    *(f16x4*)&fcwb[col * FSTR + k] = hv;
  }
}

// fp32 LSTM pointwise for one cell from a gate buffer + packed f16x2 store.
// fast: sc0 store (write-through to XCD L2)   slow: agent atomic store.
__device__ __forceinline__ void pointwise_store(const float* gb, int row, int d0, float* cv,
                                                unsigned* __restrict__ hout, int g, int cg,
                                                int sub, int fast) {
  const float* gr = gb + row * GSTR + d0;
  union { unsigned u; f16x2 h; } hv;
  #pragma unroll
  for (int j = 0; j < 2; ++j) {
    float vi = gr[j], vf = gr[16 + j], vg = gr[32 + j], vo = gr[48 + j];
    cv[j] = sigf(vf) * cv[j] + sigf(vi) * tanhf(vg);
    hv.h[j] = (f16)(sigf(vo) * tanhf(cv[j]));
  }
  unsigned* p = &hout[(g * RG + row) * 256 + cg * 8 + sub];
  if (fast)
    asm volatile("global_store_dword %0, %1, off sc0" :: "v"(p), "v"(hv.u) : "memory");
  else
    __hip_atomic_store(p, hv.u, __ATOMIC_RELAXED, __HIP_MEMORY_SCOPE_AGENT);
}

__launch_bounds__(NTHREADS, 1)
__global__ void lstm_all(const int* __restrict__ xTok, const float* __restrict__ emb,
    const float* __restrict__ eWih0, const float* __restrict__ eWhh0,
    const float* __restrict__ ebih0, const float* __restrict__ ebhh0,
    const float* __restrict__ eWih1, const float* __restrict__ eWhh1,
    const float* __restrict__ ebih1, const float* __restrict__ ebhh1,
    const float* __restrict__ dWih0, const float* __restrict__ dWhh0,
    const float* __restrict__ dbih0, const float* __restrict__ dbhh0,
    const float* __restrict__ dWih1, const float* __restrict__ dWhh1,
    const float* __restrict__ dbih1, const float* __restrict__ dbhh1,
    const float* __restrict__ fcw, const float* __restrict__ fcb,
    float* __restrict__ dout, char* __restrict__ h0buf, char* __restrict__ h1buf,
    int* __restrict__ slots)
{
  __shared__ __align__(16) char upool[RG * XSTR * 2];  // enc: xe stage | dec: lbuf + w0d
  __shared__ __align__(16) f16 h0s[RG * HSTR];
  __shared__ __align__(16) f16 h1s[RG * HSTR];
  __shared__ __align__(16) f16 fcwb[ON * FSTR];
  __shared__ float gbuf0[RG * GSTR];
  __shared__ float gbuf1[RG * GSTR];
  __shared__ int amaxlds[RG];
  __shared__ int esc;
  __shared__ int fastlds;

  f16*   xes  = (f16*)upool;
  float* lbuf = (float*)upool;            // [RG][33] logits (decoder only)
  float* w0d  = (float*)(upool + 4352);   // [64][32] dec_Wih0 slice (decoder only)

  const int tid  = threadIdx.x;
  const int g    = blockIdx.x & 7;        // batch group
  const int cg   = blockIdx.x >> 3;       // col-group within group, 0..31
  const int w    = tid >> 6;              // wave = gate index 0..3
  const int lane = tid & 63;
  const int quad = lane >> 4;
  const int l16  = lane & 15;
  const int colg = w * HN + cg * 16 + l16;  // global gate column (2048-space)
  const int urow = tid >> 3;              // pointwise: row 0..31
  const int ud0  = (tid & 7) * 2;         // pointwise: dim pair base
  int ctarget = 0;                        // cumulative counter target
  if (tid == 0) esc = 0;

  int myxcc = 0;
  asm volatile("s_getreg_b32 %0, hwreg(HW_REG_XCC_ID)" : "=s"(myxcc));

  // ---- encoder weights -> register B-fragments
  f16x8 Wi0r[8], Wh0r[16], Wi1r[16], Wh1r[16];
  loadW<8>(eWih0, EN, colg, quad, Wi0r);
  loadW<16>(eWhh0, HN, colg, quad, Wh0r);
  loadW<16>(eWih1, HN, colg, quad, Wi1r);
  loadW<16>(eWhh1, HN, colg, quad, Wh1r);
  float bias0 = ebih0[colg] + ebhh0[colg];
  float bias1 = ebih1[colg] + ebhh1[colg];

  // ---- xe(0) pre-gather; zero h(-1) (parity 1) via BOTH paths; zero cells
  gatherXE(xes, xTok, emb, g, 0, tid);
  float c0[2] = {0.f, 0.f}, c1[2] = {0.f, 0.f};
  {
    unsigned idx = (unsigned)(BN * 256 + (g * RG + urow) * 256 + cg * 8 + (tid & 7));
    unsigned* p0 = (unsigned*)h0buf + idx;
    unsigned* p1 = (unsigned*)h1buf + idx;
    __hip_atomic_store(p0, 0u, __ATOMIC_RELAXED, __HIP_MEMORY_SCOPE_AGENT);
    __hip_atomic_store(p1, 0u, __ATOMIC_RELAXED, __HIP_MEMORY_SCOPE_AGENT);
    unsigned z = 0;
    asm volatile("global_store_dword %0, %1, off sc0" :: "v"(p0), "v"(z) : "memory");
    asm volatile("global_store_dword %0, %1, off sc0" :: "v"(p1), "v"(z) : "memory");
  }
  // ---- PHASE-1 INIT barrier (agent/MALL domain, R7-proven).
  // Per-wave vmcnt drain + barrier => all h-zero stores retired. tid0 then:
  // slow-counter + fast-ready cleanse (agent), drain, THEN publish init flag
  // (agent, value 1+XCC_ID). Any wg seeing all 32 flags also sees all
  // cleanses and h zeros. NOTHING L2-side is touched here (mixed-safe).
  asm volatile("s_waitcnt vmcnt(0)" ::: "memory");
  __syncthreads();
  if (tid == 0) {
    __hip_atomic_store(&slots[g * SLB + 40], 0, __ATOMIC_RELAXED, __HIP_MEMORY_SCOPE_AGENT);
    __hip_atomic_store(&slots[g * SLB + 34], 0, __ATOMIC_RELAXED, __HIP_MEMORY_SCOPE_AGENT);
    asm volatile("s_waitcnt vmcnt(0)" ::: "memory");
    __hip_atomic_store(&slots[g * SLB + cg], 1 + myxcc, __ATOMIC_RELAXED,
                       __HIP_MEMORY_SCOPE_AGENT);
  }
  int fast;
  {
    int v = 0;
    if (!esc) {
      int idx = tid & 31;
      int gd = 0;
      for (;;) {
        v = __hip_atomic_load(&slots[g * SLB + idx], __ATOMIC_RELAXED,
                              __HIP_MEMORY_SCOPE_AGENT);
        if (__all(v >= 1)) break;
        if (++gd > POLL_GUARD) { esc = 1; break; }
        __builtin_amdgcn_s_sleep(1);
      }
    }
    int ok = __all(v == 1 + myxcc) && !esc;
    if (tid == 0) fastlds = ok ? 1 : 0;
  }
  __syncthreads();
  fast = fastlds;

  // ---- PHASE-2 (fast groups only): reset fast counter at the L2 point,
  // publish fast-ready (agent), all wgs gate on it. Ensures no fast add ever
  // races the reset, and the reset never occurs in mixed-placement groups.
  if (fast) {
    if (cg == 0 && tid == 0) {
      int* pc = &slots[g * SLB + 64];
      int z = 0;
      asm volatile("global_store_dword %0, %1, off sc0" :: "v"(pc), "v"(z) : "memory");
      asm volatile("s_waitcnt vmcnt(0)" ::: "memory");
      __hip_atomic_store(&slots[g * SLB + 34], 1, __ATOMIC_RELAXED, __HIP_MEMORY_SCOPE_AGENT);
    } else if (cg != 0 && tid == 0) {
      int gd = 0;
      while (__hip_atomic_load(&slots[g * SLB + 34], __ATOMIC_RELAXED,
                               __HIP_MEMORY_SCOPE_AGENT) < 1) {
        if (++gd > POLL_GUARD) { esc = 1; break; }
        __builtin_amdgcn_s_sleep(1);
      }
    }
    __syncthreads();
    asm volatile("buffer_inv" ::: "memory");
  }

  // ================= encoder: interval k does cell0@k + cell1@(k-1)
  for (int k = 0; k <= SN; ++k) {
    u32x4 v0[8], v1[8];
    issue8(v0, h0buf + (size_t)((k - 1) & 1) * BN * HN * 2 + (size_t)(g * RG) * HN * 2, tid, fast);
    if (k >= 1)
      issue8(v1, h1buf + (size_t)(k & 1) * BN * HN * 2 + (size_t)(g * RG) * HN * 2, tid, fast);

    f32x4 acc0[2], acc1[2];
    if (k < SN) {   // xe part of cell0 overlaps the stage loads
      f32x4 b0; b0[0] = bias0; b0[1] = bias0; b0[2] = bias0; b0[3] = bias0;
      acc0[0] = b0; acc0[1] = b0;
      matmulAcc<8>(acc0, xes, XSTR, Wi0r, l16, quad);
    }
    if (k >= 1) asm volatile("s_waitcnt vmcnt(8)" ::: "memory");  // h0 batch retired
    else        asm volatile("s_waitcnt vmcnt(0)" ::: "memory");
    write8(h0s, v0, tid);
    __syncthreads();
    if (k < SN) matmulAcc<16>(acc0, h0s, HSTR, Wh0r, l16, quad);   // h1 still in flight
    if (k >= 1) {
      f32x4 b1; b1[0] = bias1; b1[1] = bias1; b1[2] = bias1; b1[3] = bias1;
      acc1[0] = b1; acc1[1] = b1;
      matmulAcc<16>(acc1, h0s, HSTR, Wi1r, l16, quad);
      asm volatile("s_waitcnt vmcnt(0)" ::: "memory");
      write8(h1s, v1, tid);
      __syncthreads();
      matmulAcc<16>(acc1, h1s, HSTR, Wh1r, l16, quad);
    }

    // merged exchange: both cells, one sync, one pointwise pass
    #pragma unroll
    for (int mt = 0; mt < 2; ++mt) {
      #pragma unroll
      for (int i = 0; i < 4; ++i) {
        int rr = (mt * 16 + quad * 4 + i) * GSTR + w * 16 + l16;
        if (k < SN) gbuf0[rr] = acc0[mt][i];
        if (k >= 1) gbuf1[rr] = acc1[mt][i];
      }
    }
    __syncthreads();
    if (k < SN)
      pointwise_store(gbuf0, urow, ud0, c0,
                      (unsigned*)(h0buf + (size_t)(k & 1) * BN * HN * 2), g, cg, tid & 7, fast);
    if (k >= 1)
      pointwise_store(gbuf1, urow, ud0, c1,
                      (unsigned*)(h1buf + (size_t)((k - 1) & 1) * BN * HN * 2), g, cg, tid & 7,
                      fast);

    ctarget += NCG;
    arrive_any(slots, g, tid, fast);
    if (k < SN - 1) gatherXE(xes, xTok, emb, g, k + 1, tid);   // hidden in the gap
    __syncthreads();   // gather-complete guard
    wait_any(slots, g, tid, fast, ctarget, &esc);
  }

  // ================= decoder setup: swap weight regs to decoder weights
  loadW<16>(dWhh0, HN, colg, quad, Wh0r);
  loadW<16>(dWih1, HN, colg, quad, Wi1r);
  loadW<16>(dWhh1, HN, colg, quad, Wh1r);
  bias0 = dbih0[colg] + dbhh0[colg];
  bias1 = dbih1[colg] + dbhh1[colg];
  {   // dec_Wih0 slice [64 owned cols][32 inputs] -> LDS (one-hot gather table)
    int cl = tid >> 2, i0 = (tid & 3) * 8;
    int gcol = (cl >> 4) * HN + cg * 16 + (cl & 15);
    const float* p = dWih0 + (size_t)gcol * ON + i0;
    #pragma unroll
    for (int j = 0; j < 8; ++j) w0d[cl * 32 + i0 + j] = p[j];
  }
  if (tid < RG) amaxlds[tid] = 0;   // xin(0) = one-hot(0)
  // h0s holds h0@127 (staged at k=128); h1buf parity1 = h1@127; c0,c1 carry.

  // ================= decoder: I1 = [fc+softmax+amax@(t-1)] + cell0@t ; I2 = cell1@t
  for (int t = 0; t <= SN; ++t) {
    u32x4 v0[8];
    issue8(v0, h1buf + (size_t)((t - 1) & 1) * BN * HN * 2 + (size_t)(g * RG) * HN * 2, tid, fast);
    float fb = 0.f;
    if (t >= 1) fb = fcb[(t - 1) * ON + ((w >> 1) * 16 + l16)];   // early, off-chain-ish

    f32x4 acc0[2];
    if (t < SN) {   // Whh0 part of cell0 (h0s ready) overlaps the h1 stage
      acc0[0] = f32x4{0.f, 0.f, 0.f, 0.f}; acc0[1] = acc0[0];
      matmulAcc<16>(acc0, h0s, HSTR, Wh0r, l16, quad);
    }
    asm volatile("s_waitcnt vmcnt(0)" ::: "memory");
    write8(h1s, v0, tid);
    __syncthreads();

    if (t >= 1) {
      int fmt = w & 1, fnt = w >> 1;
      int colo = fnt * 16 + l16;
      f32x4 afc = {0.f, 0.f, 0.f, 0.f};
      #pragma unroll
      for (int kt = 0; kt < 16; ++kt) {   // B-frags from LDS (prefetched in I2 gap)
        f16x8 bf = *(const f16x8*)&fcwb[colo * FSTR + kt * 32 + quad * 8];
        f16x8 av = *(const f16x8*)&h1s[(fmt * 16 + l16) * HSTR + kt * 32 + quad * 8];
        afc = MFMA16(av, bf, afc);
      }
      #pragma unroll
      for (int i = 0; i < 4; ++i)
        lbuf[(fmt * 16 + quad * 4 + i) * 33 + colo] = afc[i] + fb;
      __syncthreads();
      {   // parallel softmax + argmax: 8 threads per row, shfl_xor reductions
        int st = t - 1;
        int row = tid >> 3, s = tid & 7, cbase = s * 4;
        float vv[4];
        #pragma unroll
        for (int j = 0; j < 4; ++j) vv[j] = lbuf[row * 33 + cbase + j];
        float mx = vv[0]; int bi = cbase;
        #pragma unroll
        for (int j = 1; j < 4; ++j)
          if (vv[j] > mx) { mx = vv[j]; bi = cbase + j; }
        #pragma unroll
        for (int m = 1; m < 8; m <<= 1) {
          float om = __shfl_xor(mx, m);
          int   ob = __shfl_xor(bi, m);
          if (om > mx || (om == mx && ob < bi)) { mx = om; bi = ob; }
        }
        float e[4], ss = 0.f;
        #pragma unroll
        for (int j = 0; j < 4; ++j) { e[j] = __expf(vv[j] - mx); ss += e[j]; }
        #pragma unroll
        for (int m = 1; m < 8; m <<= 1) ss += __shfl_xor(ss, m);
        if (s == 0) amaxlds[row] = bi;
        if (cg == 0) {
          float inv = 1.0f / ss;
          float* op = dout + ((size_t)(g * RG + row) * SN + st) * ON + cbase;
          #pragma unroll
          for (int j = 0; j < 4; ++j) op[j] = e[j] * inv;
        }
      }
      __syncthreads();
    }

    if (t < SN) {   // add bias + one-hot gather(dec_Wih0, amax), then exchange
      #pragma unroll
      for (int mt = 0; mt < 2; ++mt) {
        #pragma unroll
        for (int i = 0; i < 4; ++i) {
          int row = mt * 16 + quad * 4 + i;
          acc0[mt][i] += bias0 + w0d[(w * 16 + l16) * 32 + amaxlds[row]];
        }
      }
      #pragma unroll
      for (int mt = 0; mt < 2; ++mt) {
        #pragma unroll
        for (int i = 0; i < 4; ++i)
          gbuf0[(mt * 16 + quad * 4 + i) * GSTR + w * 16 + l16] = acc0[mt][i];
      }
      __syncthreads();
      pointwise_store(gbuf0, urow, ud0, c0,
                      (unsigned*)(h0buf + (size_t)(t & 1) * BN * HN * 2), g, cg, tid & 7, fast);
    }
    ctarget += NCG;
    arrive_any(slots, g, tid, fast);
    wait_any(slots, g, tid, fast, ctarget, &esc);

    if (t < SN) {   // I2: cell1@t : h0@t@Wih1^T + h1@(t-1)@Whh1^T + b
      u32x4 v2[8];
      issue8(v2, h0buf + (size_t)(t & 1) * BN * HN * 2 + (size_t)(g * RG) * HN * 2, tid, fast);
      f32x4 acc1[2];
      f32x4 b1; b1[0] = bias1; b1[1] = bias1; b1[2] = bias1; b1[3] = bias1;
      acc1[0] = b1; acc1[1] = b1;
      matmulAcc<16>(acc1, h1s, HSTR, Wh1r, l16, quad);   // h1@(t-1), overlaps stage
      asm volatile("s_waitcnt vmcnt(0)" ::: "memory");
      write8(h0s, v2, tid);
      __syncthreads();
      matmulAcc<16>(acc1, h0s, HSTR, Wi1r, l16, quad);
      #pragma unroll
      for (int mt = 0; mt < 2; ++mt) {
        #pragma unroll
        for (int i = 0; i < 4; ++i)
          gbuf0[(mt * 16 + quad * 4 + i) * GSTR + w * 16 + l16] = acc1[mt][i];
      }
      __syncthreads();
      pointwise_store(gbuf0, urow, ud0, c1,
                      (unsigned*)(h1buf + (size_t)(t & 1) * BN * HN * 2), g, cg, tid & 7, fast);
      ctarget += NCG;
      arrive_any(slots, g, tid, fast);
      stageFCW(fcwb, fcw, t, tid);   // fcw[st=t] for next I1 — hidden in the gap
      __syncthreads();               // staging-complete guard
      wait_any(slots, g, tid, fast, ctarget, &esc);
    }
  }
}

extern "C" void kernel_launch(void* const* d_in, const int* in_sizes, int n_in,
                              void* d_out, int out_size, void* d_ws, size_t ws_size,
                              hipStream_t stream) {
  (void)in_sizes; (void)n_in; (void)out_size; (void)ws_size;
  const int*   xTok  = (const int*)d_in[0];
  const float* emb   = (const float*)d_in[1];
  const float* eWih0 = (const float*)d_in[2];
  const float* eWhh0 = (const float*)d_in[3];
  const float* ebih0 = (const float*)d_in[4];
  const float* ebhh0 = (const float*)d_in[5];
  const float* eWih1 = (const float*)d_in[6];
  const float* eWhh1 = (const float*)d_in[7];
  const float* ebih1 = (const float*)d_in[8];
  const float* ebhh1 = (const float*)d_in[9];
  const float* dWih0 = (const float*)d_in[10];
  const float* dWhh0 = (const float*)d_in[11];
  const float* dbih0 = (const float*)d_in[12];
  const float* dbhh0 = (const float*)d_in[13];
  const float* dWih1 = (const float*)d_in[14];
  const float* dWhh1 = (const float*)d_in[15];
  const float* dbih1 = (const float*)d_in[16];
  const float* dbhh1 = (const float*)d_in[17];
  const float* fcw   = (const float*)d_in[18];
  const float* fcb   = (const float*)d_in[19];

  // ws layout: h0buf [2][256][512] f16 (512KB) | h1buf (512KB) |
  // slots [8][128] int (4KB; per group: [0..31] init flags [agent, 1+XCC],
  // [34] fast-ready [agent], [40] slow counter [MALL], [64] fast counter [L2])
  char* h0buf = (char*)d_ws;
  char* h1buf = (char*)d_ws + (size_t)2 * BN * HN * 2;
  int*  slots = (int*)((char*)d_ws + (size_t)4 * BN * HN * 2);

  hipLaunchKernelGGL(lstm_all, dim3(256), dim3(NTHREADS), 0, stream,
                     xTok, emb, eWih0, eWhh0, ebih0, ebhh0, eWih1, eWhh1, ebih1, ebhh1,
                     dWih0, dWhh0, dbih0, dbhh0, dWih1, dWhh1, dbih1, dbhh1,
                     fcw, fcb, (float*)d_out, h0buf, h1buf, slots);
}

// Round 5
// 2679.026 us; speedup vs baseline: 42.9072x; 1.0552x over previous
//
#include <hip/hip_runtime.h>

// ---------------------------------------------------------------------------
// NER LSTM (B=256,S=128,E=256,H=512,O=32) — one persistent kernel.
// 256 wgs x 256 threads, 1 block/CU. 8 batch groups (32 rows) x 32 col-group
// wgs (g=blockIdx&7). Recurrent weights in VGPRs as f16 MFMA B-frags.
// R12 = proven-ingredients-only composition (R8/R11 novel flag protocols both
// raced; no more protocol invention):
//  - Barrier (BOTH paths): verbatim R7. Arrive = per-wave vmcnt drain +
//    __syncthreads + tid0 fire-and-forget global_atomic_add on the group's
//    MALL counter. Wait = ALL waves poll the counter with relaxed agent
//    LOADS (loads broadcast; R10's tid0 RMW polling serialized 32 CUs on
//    line ownership and cost ~+1us/round — removed).
//  - Data transport: R10-proven. XCC-uniform groups (verdict via 1+XCC_ID
//    init flags) use sc0 stores/loads (XCD L2); each wave executes ONE
//    buffer_inv after observing the barrier counter, before any data loads —
//    R10 proved bit-exact: arriver drained sc0 stores to L2 before its
//    atomic, so post-inv L1 fills are final data. Mixed groups: sc1 (R7).
//  - Keeps R9's conflict-free stageFCW / gatherXE remaps (bit-identical,
//    passed in R10).
// ---------------------------------------------------------------------------

#define BN 256
#define SN 128
#define EN 256
#define HN 512
#define ON 32
#define RG 32          // batch rows per group
#define NCG 32         // col-group wgs per group
#define NTHREADS 256
#define XSTR 264       // xe stage row stride (f16): 256 + 8 pad
#define HSTR 520       // h  stage row stride (f16): 512 + 8 pad
#define FSTR 520       // fcw stage row stride (f16): 512 + 8 pad
#define GSTR 68        // gbuf row stride (floats): 64 + 4 pad
#define POLL_GUARD (1 << 20)
#define SLB 128        // slots ints per group: [0..31] init flags (1+XCC),
                       // [40] barrier counter (MALL)

typedef _Float16 f16;
typedef _Float16 f16x8 __attribute__((ext_vector_type(8)));
typedef _Float16 f16x4 __attribute__((ext_vector_type(4)));
typedef _Float16 f16x2 __attribute__((ext_vector_type(2)));
typedef float f32x4 __attribute__((ext_vector_type(4)));
typedef unsigned u32x4 __attribute__((ext_vector_type(4)));

__device__ __forceinline__ f32x4 MFMA16(f16x8 a, f16x8 b, f32x4 c) {
  return __builtin_amdgcn_mfma_f32_16x16x32_f16(a, b, c, 0, 0, 0);
}

__device__ __forceinline__ float sigf(float x) { return 1.0f / (1.0f + __expf(-x)); }

// Load B-fragment slice of W [4H x K] (row-major) for column `col`:
// lane holds W[col][kt*32 + quad*8 + j], j=0..7.
template<int NKT>
__device__ __forceinline__ void loadW(const float* __restrict__ Wb, int K, int col, int quad,
                                      f16x8* dst) {
  #pragma unroll
  for (int kt = 0; kt < NKT; ++kt) {
    const float* p = Wb + (size_t)col * K + kt * 32 + quad * 8;
    f32x4 a = *(const f32x4*)p;
    f32x4 b = *(const f32x4*)(p + 4);
    f16x8 h;
    h[0] = (f16)a[0]; h[1] = (f16)a[1]; h[2] = (f16)a[2]; h[3] = (f16)a[3];
    h[4] = (f16)b[0]; h[5] = (f16)b[1]; h[6] = (f16)b[2]; h[7] = (f16)b[3];
    dst[kt] = h;
  }
}

// Issue 8 batched dwordx4 stage loads for one [RG x HN] f16 tile (32KB).
// fast: sc0 (XCD L2; L1 freshness via barrier-exit buffer_inv)  slow: sc1.
__device__ __forceinline__ void issue8(u32x4* v, const char* __restrict__ src, int tid,
                                       int fast) {
  const char* base = src + tid * 16;
  if (fast) {
    #pragma unroll
    for (int j = 0; j < 8; ++j)
      asm volatile("global_load_dwordx4 %0, %1, off sc0" : "=v"(v[j]) : "v"(base + j * 4096));
  } else {
    #pragma unroll
    for (int j = 0; j < 8; ++j)
      asm volatile("global_load_dwordx4 %0, %1, off sc1" : "=v"(v[j]) : "v"(base + j * 4096));
  }
}
// Scatter the 8 loaded vectors into padded LDS (call after the waitcnt).
__device__ __forceinline__ void write8(f16* dst, const u32x4* v, int tid) {
  #pragma unroll
  for (int j = 0; j < 8; ++j) {
    int u = j * 256 + tid, rr = u >> 6, cc = u & 63;
    *(u32x4*)&dst[rr * HSTR + cc * 8] = v[j];
  }
}

// acc[mt] += stage(rows mt*16..) x Wr   (A[m=lane&15][k=quad*8+j] layout)
template<int NKT>
__device__ __forceinline__ void matmulAcc(f32x4* acc, const f16* stage, int stride,
                                          const f16x8* Wr, int l16, int quad) {
  #pragma unroll
  for (int mt = 0; mt < 2; ++mt) {
    #pragma unroll
    for (int kt = 0; kt < NKT; ++kt) {
      f16x8 a = *(const f16x8*)&stage[(mt * 16 + l16) * stride + kt * 32 + quad * 8];
      acc[mt] = MFMA16(a, Wr[kt], acc[mt]);
    }
  }
}

// Barrier arrive (R7-proven, both paths): every wave drains its own vmcnt
// (covers the asm sc0/sc1 h-stores), then barrier, then tid0 fires ONE
// fire-and-forget atomic add on the group's MALL counter.
__device__ __forceinline__ void arrive_any(int* slots, int g, int tid) {
  asm volatile("s_waitcnt vmcnt(0)" ::: "memory");
  __syncthreads();
  if (tid == 0) {
    int one = 1;
    int* p = &slots[g * SLB + 40];
    asm volatile("global_atomic_add %0, %1, off" :: "v"(p), "v"(one) : "memory");
  }
}

// Barrier wait (R7-proven): all waves poll the counter with relaxed agent
// LOADS until >= ctarget. Fast groups then execute one buffer_inv per wave
// (R10-proven): every subsequent sc0 data load fills L1 from the XCD L2,
// which holds final data (arrivers drained stores before their atomic).
__device__ __forceinline__ void wait_any(int* slots, int g, int fast, int ctarget, int* esc) {
  if (!*esc) {
    const int* p = &slots[g * SLB + 40];
    int gd = 0;
    for (;;) {
      int v = __hip_atomic_load(p, __ATOMIC_RELAXED, __HIP_MEMORY_SCOPE_AGENT);
      if (v >= ctarget) break;
      if (++gd > POLL_GUARD) { *esc = 1; break; }
      __builtin_amdgcn_s_sleep(1);
    }
  }
  if (fast) asm volatile("buffer_inv" ::: "memory");
  asm volatile("" ::: "memory");
}

// Gather one time-step of embeddings for the group's 32 rows -> xes (f16).
// r=tid&31, sub=tid>>5: octet lanes hit distinct bank groups (conflict-free).
__device__ __forceinline__ void gatherXE(f16* xes, const int* __restrict__ xTok,
                                         const float* __restrict__ emb, int g, int k, int tid) {
  int r = tid & 31, sub = tid >> 5;
  int tok = xTok[(g * RG + r) * SN + k];
  const float* er = emb + (size_t)tok * EN + sub * 32;
  f16* dst = &xes[r * XSTR + sub * 32];
  #pragma unroll
  for (int jj = 0; jj < 32; jj += 8) {
    f32x4 a = *(const f32x4*)(er + jj);
    f32x4 b = *(const f32x4*)(er + jj + 4);
    f16x8 hv;
    hv[0] = (f16)a[0]; hv[1] = (f16)a[1]; hv[2] = (f16)a[2]; hv[3] = (f16)a[3];
    hv[4] = (f16)b[0]; hv[5] = (f16)b[1]; hv[6] = (f16)b[2]; hv[7] = (f16)b[3];
    *(f16x8*)(dst + jj) = hv;
  }
}

// Stage fcw[st] ([ON][HN] fp32) -> LDS f16. Thread t handles f32x4 vectors
// t + j*256: coalesced 1KB/wave global reads, conflict-free ds_write_b64.
// Same RTE cvt per element as before => bit-identical logits.
__device__ __forceinline__ void stageFCW(f16* fcwb, const float* __restrict__ fcw,
                                         int st, int tid) {
  const float* base = fcw + (size_t)st * ON * HN;
  #pragma unroll
  for (int j = 0; j < 16; ++j) {
    int fo = (tid + j * 256) * 4;        // float offset 0..16380
    int col = fo >> 9, k = fo & 511;
    f32x4 a = *(const f32x4*)(base + fo);
    f16x4 hv;
    hv[0] = (f16)a[0]; hv[1] = (f16)a[1]; hv[2] = (f16)a[2]; hv[3] = (f16)a[3];
    *(f16x4*)&fcwb[col * FSTR + k] = hv;
  }
}

// fp32 LSTM pointwise for one cell from a gate buffer + packed f16x2 store.
// fast: sc0 store (write-through to XCD L2)   slow: agent atomic store.
__device__ __forceinline__ void pointwise_store(const float* gb, int row, int d0, float* cv,
                                                unsigned* __restrict__ hout, int g, int cg,
                                                int sub, int fast) {
  const float* gr = gb + row * GSTR + d0;
  union { unsigned u; f16x2 h; } hv;
  #pragma unroll
  for (int j = 0; j < 2; ++j) {
    float vi = gr[j], vf = gr[16 + j], vg = gr[32 + j], vo = gr[48 + j];
    cv[j] = sigf(vf) * cv[j] + sigf(vi) * tanhf(vg);
    hv.h[j] = (f16)(sigf(vo) * tanhf(cv[j]));
  }
  unsigned* p = &hout[(g * RG + row) * 256 + cg * 8 + sub];
  if (fast)
    asm volatile("global_store_dword %0, %1, off sc0" :: "v"(p), "v"(hv.u) : "memory");
  else
    __hip_atomic_store(p, hv.u, __ATOMIC_RELAXED, __HIP_MEMORY_SCOPE_AGENT);
}

__launch_bounds__(NTHREADS, 1)
__global__ void lstm_all(const int* __restrict__ xTok, const float* __restrict__ emb,
    const float* __restrict__ eWih0, const float* __restrict__ eWhh0,
    const float* __restrict__ ebih0, const float* __restrict__ ebhh0,
    const float* __restrict__ eWih1, const float* __restrict__ eWhh1,
    const float* __restrict__ ebih1, const float* __restrict__ ebhh1,
    const float* __restrict__ dWih0, const float* __restrict__ dWhh0,
    const float* __restrict__ dbih0, const float* __restrict__ dbhh0,
    const float* __restrict__ dWih1, const float* __restrict__ dWhh1,
    const float* __restrict__ dbih1, const float* __restrict__ dbhh1,
    const float* __restrict__ fcw, const float* __restrict__ fcb,
    float* __restrict__ dout, char* __restrict__ h0buf, char* __restrict__ h1buf,
    int* __restrict__ slots)
{
  __shared__ __align__(16) char upool[RG * XSTR * 2];  // enc: xe stage | dec: lbuf + w0d
  __shared__ __align__(16) f16 h0s[RG * HSTR];
  __shared__ __align__(16) f16 h1s[RG * HSTR];
  __shared__ __align__(16) f16 fcwb[ON * FSTR];
  __shared__ float gbuf0[RG * GSTR];
  __shared__ float gbuf1[RG * GSTR];
  __shared__ int amaxlds[RG];
  __shared__ int esc;
  __shared__ int fastlds;

  f16*   xes  = (f16*)upool;
  float* lbuf = (float*)upool;            // [RG][33] logits (decoder only)
  float* w0d  = (float*)(upool + 4352);   // [64][32] dec_Wih0 slice (decoder only)

  const int tid  = threadIdx.x;
  const int g    = blockIdx.x & 7;        // batch group
  const int cg   = blockIdx.x >> 3;       // col-group within group, 0..31
  const int w    = tid >> 6;              // wave = gate index 0..3
  const int lane = tid & 63;
  const int quad = lane >> 4;
  const int l16  = lane & 15;
  const int colg = w * HN + cg * 16 + l16;  // global gate column (2048-space)
  const int urow = tid >> 3;              // pointwise: row 0..31
  const int ud0  = (tid & 7) * 2;         // pointwise: dim pair base
  int ctarget = 0;                        // cumulative counter target
  if (tid == 0) esc = 0;

  int myxcc = 0;
  asm volatile("s_getreg_b32 %0, hwreg(HW_REG_XCC_ID)" : "=s"(myxcc));

  // ---- encoder weights -> register B-fragments
  f16x8 Wi0r[8], Wh0r[16], Wi1r[16], Wh1r[16];
  loadW<8>(eWih0, EN, colg, quad, Wi0r);
  loadW<16>(eWhh0, HN, colg, quad, Wh0r);
  loadW<16>(eWih1, HN, colg, quad, Wi1r);
  loadW<16>(eWhh1, HN, colg, quad, Wh1r);
  float bias0 = ebih0[colg] + ebhh0[colg];
  float bias1 = ebih1[colg] + ebhh1[colg];

  // ---- xe(0) pre-gather; zero h(-1) (parity 1) via BOTH paths; zero cells
  gatherXE(xes, xTok, emb, g, 0, tid);
  float c0[2] = {0.f, 0.f}, c1[2] = {0.f, 0.f};
  {
    unsigned idx = (unsigned)(BN * 256 + (g * RG + urow) * 256 + cg * 8 + (tid & 7));
    unsigned* p0 = (unsigned*)h0buf + idx;
    unsigned* p1 = (unsigned*)h1buf + idx;
    __hip_atomic_store(p0, 0u, __ATOMIC_RELAXED, __HIP_MEMORY_SCOPE_AGENT);
    __hip_atomic_store(p1, 0u, __ATOMIC_RELAXED, __HIP_MEMORY_SCOPE_AGENT);
    unsigned z = 0;
    asm volatile("global_store_dword %0, %1, off sc0" :: "v"(p0), "v"(z) : "memory");
    asm volatile("global_store_dword %0, %1, off sc0" :: "v"(p1), "v"(z) : "memory");
  }
  // ---- INIT barrier (agent/MALL domain, R7-proven).
  // Per-wave vmcnt drain + barrier => all h-zero stores (both paths) retired.
  // tid0 then: counter reset (agent), drain, THEN publish init flag (agent,
  // value 1+XCC_ID). Any wg seeing all 32 flags sees the reset and h zeros.
  asm volatile("s_waitcnt vmcnt(0)" ::: "memory");
  __syncthreads();
  if (tid == 0) {
    __hip_atomic_store(&slots[g * SLB + 40], 0, __ATOMIC_RELAXED, __HIP_MEMORY_SCOPE_AGENT);
    asm volatile("s_waitcnt vmcnt(0)" ::: "memory");
    __hip_atomic_store(&slots[g * SLB + cg], 1 + myxcc, __ATOMIC_RELAXED,
                       __HIP_MEMORY_SCOPE_AGENT);
  }
  int fast;
  {
    int v = 0;
    if (!esc) {
      int idx = tid & 31;
      int gd = 0;
      for (;;) {
        v = __hip_atomic_load(&slots[g * SLB + idx], __ATOMIC_RELAXED,
                              __HIP_MEMORY_SCOPE_AGENT);
        if (__all(v >= 1)) break;
        if (++gd > POLL_GUARD) { esc = 1; break; }
        __builtin_amdgcn_s_sleep(1);
      }
    }
    int ok = __all(v == 1 + myxcc) && !esc;
    if (tid == 0) fastlds = ok ? 1 : 0;
  }
  __syncthreads();
  fast = fastlds;
  if (fast) asm volatile("buffer_inv" ::: "memory");

  // ================= encoder: interval k does cell0@k + cell1@(k-1)
  for (int k = 0; k <= SN; ++k) {
    u32x4 v0[8], v1[8];
    issue8(v0, h0buf + (size_t)((k - 1) & 1) * BN * HN * 2 + (size_t)(g * RG) * HN * 2, tid, fast);
    if (k >= 1)
      issue8(v1, h1buf + (size_t)(k & 1) * BN * HN * 2 + (size_t)(g * RG) * HN * 2, tid, fast);

    f32x4 acc0[2], acc1[2];
    if (k < SN) {   // xe part of cell0 overlaps the stage loads
      f32x4 b0; b0[0] = bias0; b0[1] = bias0; b0[2] = bias0; b0[3] = bias0;
      acc0[0] = b0; acc0[1] = b0;
      matmulAcc<8>(acc0, xes, XSTR, Wi0r, l16, quad);
    }
    if (k >= 1) asm volatile("s_waitcnt vmcnt(8)" ::: "memory");  // h0 batch retired
    else        asm volatile("s_waitcnt vmcnt(0)" ::: "memory");
    write8(h0s, v0, tid);
    __syncthreads();
    if (k < SN) matmulAcc<16>(acc0, h0s, HSTR, Wh0r, l16, quad);   // h1 still in flight
    if (k >= 1) {
      f32x4 b1; b1[0] = bias1; b1[1] = bias1; b1[2] = bias1; b1[3] = bias1;
      acc1[0] = b1; acc1[1] = b1;
      matmulAcc<16>(acc1, h0s, HSTR, Wi1r, l16, quad);
      asm volatile("s_waitcnt vmcnt(0)" ::: "memory");
      write8(h1s, v1, tid);
      __syncthreads();
      matmulAcc<16>(acc1, h1s, HSTR, Wh1r, l16, quad);
    }

    // merged exchange: both cells, one sync, one pointwise pass
    #pragma unroll
    for (int mt = 0; mt < 2; ++mt) {
      #pragma unroll
      for (int i = 0; i < 4; ++i) {
        int rr = (mt * 16 + quad * 4 + i) * GSTR + w * 16 + l16;
        if (k < SN) gbuf0[rr] = acc0[mt][i];
        if (k >= 1) gbuf1[rr] = acc1[mt][i];
      }
    }
    __syncthreads();
    if (k < SN)
      pointwise_store(gbuf0, urow, ud0, c0,
                      (unsigned*)(h0buf + (size_t)(k & 1) * BN * HN * 2), g, cg, tid & 7, fast);
    if (k >= 1)
      pointwise_store(gbuf1, urow, ud0, c1,
                      (unsigned*)(h1buf + (size_t)((k - 1) & 1) * BN * HN * 2), g, cg, tid & 7,
                      fast);

    ctarget += NCG;
    arrive_any(slots, g, tid);
    if (k < SN - 1) gatherXE(xes, xTok, emb, g, k + 1, tid);   // hidden in the gap
    __syncthreads();   // gather-complete guard
    wait_any(slots, g, fast, ctarget, &esc);
  }

  // ================= decoder setup: swap weight regs to decoder weights
  loadW<16>(dWhh0, HN, colg, quad, Wh0r);
  loadW<16>(dWih1, HN, colg, quad, Wi1r);
  loadW<16>(dWhh1, HN, colg, quad, Wh1r);
  bias0 = dbih0[colg] + dbhh0[colg];
  bias1 = dbih1[colg] + dbhh1[colg];
  {   // dec_Wih0 slice [64 owned cols][32 inputs] -> LDS (one-hot gather table)
    int cl = tid >> 2, i0 = (tid & 3) * 8;
    int gcol = (cl >> 4) * HN + cg * 16 + (cl & 15);
    const float* p = dWih0 + (size_t)gcol * ON + i0;
    #pragma unroll
    for (int j = 0; j < 8; ++j) w0d[cl * 32 + i0 + j] = p[j];
  }
  if (tid < RG) amaxlds[tid] = 0;   // xin(0) = one-hot(0)
  // h0s holds h0@127 (staged at k=128); h1buf parity1 = h1@127; c0,c1 carry.

  // ================= decoder: I1 = [fc+softmax+amax@(t-1)] + cell0@t ; I2 = cell1@t
  for (int t = 0; t <= SN; ++t) {
    u32x4 v0[8];
    issue8(v0, h1buf + (size_t)((t - 1) & 1) * BN * HN * 2 + (size_t)(g * RG) * HN * 2, tid, fast);
    float fb = 0.f;
    if (t >= 1) fb = fcb[(t - 1) * ON + ((w >> 1) * 16 + l16)];   // early, off-chain-ish

    f32x4 acc0[2];
    if (t < SN) {   // Whh0 part of cell0 (h0s ready) overlaps the h1 stage
      acc0[0] = f32x4{0.f, 0.f, 0.f, 0.f}; acc0[1] = acc0[0];
      matmulAcc<16>(acc0, h0s, HSTR, Wh0r, l16, quad);
    }
    asm volatile("s_waitcnt vmcnt(0)" ::: "memory");
    write8(h1s, v0, tid);
    __syncthreads();

    if (t >= 1) {
      int fmt = w & 1, fnt = w >> 1;
      int colo = fnt * 16 + l16;
      f32x4 afc = {0.f, 0.f, 0.f, 0.f};
      #pragma unroll
      for (int kt = 0; kt < 16; ++kt) {   // B-frags from LDS (prefetched in I2 gap)
        f16x8 bf = *(const f16x8*)&fcwb[colo * FSTR + kt * 32 + quad * 8];
        f16x8 av = *(const f16x8*)&h1s[(fmt * 16 + l16) * HSTR + kt * 32 + quad * 8];
        afc = MFMA16(av, bf, afc);
      }
      #pragma unroll
      for (int i = 0; i < 4; ++i)
        lbuf[(fmt * 16 + quad * 4 + i) * 33 + colo] = afc[i] + fb;
      __syncthreads();
      {   // parallel softmax + argmax: 8 threads per row, shfl_xor reductions
        int st = t - 1;
        int row = tid >> 3, s = tid & 7, cbase = s * 4;
        float vv[4];
        #pragma unroll
        for (int j = 0; j < 4; ++j) vv[j] = lbuf[row * 33 + cbase + j];
        float mx = vv[0]; int bi = cbase;
        #pragma unroll
        for (int j = 1; j < 4; ++j)
          if (vv[j] > mx) { mx = vv[j]; bi = cbase + j; }
        #pragma unroll
        for (int m = 1; m < 8; m <<= 1) {
          float om = __shfl_xor(mx, m);
          int   ob = __shfl_xor(bi, m);
          if (om > mx || (om == mx && ob < bi)) { mx = om; bi = ob; }
        }
        float e[4], ss = 0.f;
        #pragma unroll
        for (int j = 0; j < 4; ++j) { e[j] = __expf(vv[j] - mx); ss += e[j]; }
        #pragma unroll
        for (int m = 1; m < 8; m <<= 1) ss += __shfl_xor(ss, m);
        if (s == 0) amaxlds[row] = bi;
        if (cg == 0) {
          float inv = 1.0f / ss;
          float* op = dout + ((size_t)(g * RG + row) * SN + st) * ON + cbase;
          #pragma unroll
          for (int j = 0; j < 4; ++j) op[j] = e[j] * inv;
        }
      }
      __syncthreads();
    }

    if (t < SN) {   // add bias + one-hot gather(dec_Wih0, amax), then exchange
      #pragma unroll
      for (int mt = 0; mt < 2; ++mt) {
        #pragma unroll
        for (int i = 0; i < 4; ++i) {
          int row = mt * 16 + quad * 4 + i;
          acc0[mt][i] += bias0 + w0d[(w * 16 + l16) * 32 + amaxlds[row]];
        }
      }
      #pragma unroll
      for (int mt = 0; mt < 2; ++mt) {
        #pragma unroll
        for (int i = 0; i < 4; ++i)
          gbuf0[(mt * 16 + quad * 4 + i) * GSTR + w * 16 + l16] = acc0[mt][i];
      }
      __syncthreads();
      pointwise_store(gbuf0, urow, ud0, c0,
                      (unsigned*)(h0buf + (size_t)(t & 1) * BN * HN * 2), g, cg, tid & 7, fast);
    }
    ctarget += NCG;
    arrive_any(slots, g, tid);
    wait_any(slots, g, fast, ctarget, &esc);

    if (t < SN) {   // I2: cell1@t : h0@t@Wih1^T + h1@(t-1)@Whh1^T + b
      u32x4 v2[8];
      issue8(v2, h0buf + (size_t)(t & 1) * BN * HN * 2 + (size_t)(g * RG) * HN * 2, tid, fast);
      f32x4 acc1[2];
      f32x4 b1; b1[0] = bias1; b1[1] = bias1; b1[2] = bias1; b1[3] = bias1;
      acc1[0] = b1; acc1[1] = b1;
      matmulAcc<16>(acc1, h1s, HSTR, Wh1r, l16, quad);   // h1@(t-1), overlaps stage
      asm volatile("s_waitcnt vmcnt(0)" ::: "memory");
      write8(h0s, v2, tid);
      __syncthreads();
      matmulAcc<16>(acc1, h0s, HSTR, Wi1r, l16, quad);
      #pragma unroll
      for (int mt = 0; mt < 2; ++mt) {
        #pragma unroll
        for (int i = 0; i < 4; ++i)
          gbuf0[(mt * 16 + quad * 4 + i) * GSTR + w * 16 + l16] = acc1[mt][i];
      }
      __syncthreads();
      pointwise_store(gbuf0, urow, ud0, c1,
                      (unsigned*)(h1buf + (size_t)(t & 1) * BN * HN * 2), g, cg, tid & 7, fast);
      ctarget += NCG;
      arrive_any(slots, g, tid);
      stageFCW(fcwb, fcw, t, tid);   // fcw[st=t] for next I1 — hidden in the gap
      __syncthreads();               // staging-complete guard
      wait_any(slots, g, fast, ctarget, &esc);
    }
  }
}

extern "C" void kernel_launch(void* const* d_in, const int* in_sizes, int n_in,
                              void* d_out, int out_size, void* d_ws, size_t ws_size,
                              hipStream_t stream) {
  (void)in_sizes; (void)n_in; (void)out_size; (void)ws_size;
  const int*   xTok  = (const int*)d_in[0];
  const float* emb   = (const float*)d_in[1];
  const float* eWih0 = (const float*)d_in[2];
  const float* eWhh0 = (const float*)d_in[3];
  const float* ebih0 = (const float*)d_in[4];
  const float* ebhh0 = (const float*)d_in[5];
  const float* eWih1 = (const float*)d_in[6];
  const float* eWhh1 = (const float*)d_in[7];
  const float* ebih1 = (const float*)d_in[8];
  const float* ebhh1 = (const float*)d_in[9];
  const float* dWih0 = (const float*)d_in[10];
  const float* dWhh0 = (const float*)d_in[11];
  const float* dbih0 = (const float*)d_in[12];
  const float* dbhh0 = (const float*)d_in[13];
  const float* dWih1 = (const float*)d_in[14];
  const float* dWhh1 = (const float*)d_in[15];
  const float* dbih1 = (const float*)d_in[16];
  const float* dbhh1 = (const float*)d_in[17];
  const float* fcw   = (const float*)d_in[18];
  const float* fcb   = (const float*)d_in[19];

  // ws layout: h0buf [2][256][512] f16 (512KB) | h1buf (512KB) |
  // slots [8][128] int (4KB; per group: [0..31] init flags [agent, 1+XCC],
  // [40] barrier counter [MALL])
  char* h0buf = (char*)d_ws;
  char* h1buf = (char*)d_ws + (size_t)2 * BN * HN * 2;
  int*  slots = (int*)((char*)d_ws + (size_t)4 * BN * HN * 2);

  hipLaunchKernelGGL(lstm_all, dim3(256), dim3(NTHREADS), 0, stream,
                     xTok, emb, eWih0, eWhh0, ebih0, ebhh0, eWih1, eWhh1, ebih1, ebhh1,
                     dWih0, dWhh0, dbih0, dbhh0, dWih1, dWhh1, dbih1, dbhh1,
                     fcw, fcb, (float*)d_out, h0buf, h1buf, slots);
}